// Round 1
// baseline (38.348 us; speedup 1.0000x reference)
//
#include <hip/hip_runtime.h>
#include <math.h>

#define NPART 2048
#define B 64
#define N 54
#define E 54
#define C 5
#define LOG_CLAMP (-100.0f)

// ---------------- Kernel 1: big MSE partial reduction ----------------
__global__ __launch_bounds__(256) void k_mse_partial(const float* __restrict__ pred,
                                                     const float* __restrict__ ref,
                                                     float* __restrict__ part, int n4) {
    const float4* p4 = (const float4*)pred;
    const float4* r4 = (const float4*)ref;
    float acc = 0.0f;
    int idx = blockIdx.x * blockDim.x + threadIdx.x;
    int stride = gridDim.x * blockDim.x;
    for (int i = idx; i < n4; i += stride) {
        float4 a = p4[i];
        float4 b = r4[i];
        float d0 = a.x - b.x, d1 = a.y - b.y, d2 = a.z - b.z, d3 = a.w - b.w;
        acc = fmaf(d0, d0, acc);
        acc = fmaf(d1, d1, acc);
        acc = fmaf(d2, d2, acc);
        acc = fmaf(d3, d3, acc);
    }
    // wave (64-lane) reduction
    #pragma unroll
    for (int off = 32; off > 0; off >>= 1) acc += __shfl_down(acc, off, 64);
    __shared__ float s[4];
    int lane = threadIdx.x & 63;
    int w = threadIdx.x >> 6;
    if (lane == 0) s[w] = acc;
    __syncthreads();
    if (threadIdx.x == 0) part[blockIdx.x] = s[0] + s[1] + s[2] + s[3];
}

// ---------------- Kernel 2: per-batch argmin + CE + BCE ----------------
__global__ __launch_bounds__(64) void k_batch(const float* __restrict__ pred_nodes,
                                              const float* __restrict__ pred_edges,
                                              const float* __restrict__ ref_nodes,
                                              const float* __restrict__ ref_edges,
                                              const int* __restrict__ ref_term,
                                              float* __restrict__ out_min_inds,
                                              float* __restrict__ nll_class,
                                              float* __restrict__ nll_edge) {
    int b = blockIdx.x;
    int t = threadIdx.x; // 64 threads, one wave
    const float* pn = pred_nodes + b * (3 + C);
    float px = pn[0], py = pn[1], pz = pn[2];

    // distance^2 for node t
    float d2 = 1e30f;
    if (t < N) {
        const float* rn = ref_nodes + ((long)b * N + t) * 4;
        float dx = rn[0] - px, dy = rn[1] - py, dz = rn[2] - pz;
        d2 = dx * dx + dy * dy + dz * dz;
    }
    int mi = t;
    // min-reduce with first-index tie-break (matches jnp.argmin)
    #pragma unroll
    for (int off = 32; off > 0; off >>= 1) {
        float od = __shfl_down(d2, off, 64);
        int oi = __shfl_down(mi, off, 64);
        if (od < d2 || (od == d2 && oi < mi)) { d2 = od; mi = oi; }
    }
    mi = __shfl(mi, 0, 64); // broadcast argmin

    // class CE (wave-uniform, computed by all lanes - cheap)
    int tgt = (int)ref_nodes[((long)b * N + mi) * 4 + 3];
    const float* logits = pn + 3;
    float m = logits[0];
    #pragma unroll
    for (int c = 1; c < C; c++) m = fmaxf(m, logits[c]);
    float se = 0.0f;
    #pragma unroll
    for (int c = 0; c < C; c++) se += __expf(logits[c] - m);
    float ce = logf(se) + m - logits[tgt];

    // edge BCE: lane t handles edge t
    float term = 0.0f;
    if (t < E) {
        float sel = ref_edges[((long)b * N + mi) * E + t];
        float p = pred_edges[b * E + t];
        float lp = fmaxf(logf(p), LOG_CLAMP);
        float l1mp = fmaxf(log1pf(-p), LOG_CLAMP);
        term = -(sel * lp + (1.0f - sel) * l1mp);
    }
    #pragma unroll
    for (int off = 32; off > 0; off >>= 1) term += __shfl_down(term, off, 64);

    if (t == 0) {
        float active = (ref_term[b] == 0) ? 1.0f : 0.0f;
        float bce = term / (float)E;
        float ne = active * bce;
        if (isnan(ne)) ne = 0.0f;
        nll_class[b] = active * ce;
        nll_edge[b] = ne;
        out_min_inds[b] = (float)mi;
    }
}

// ---------------- Kernel 3: finalize ----------------
__global__ __launch_bounds__(256) void k_final(const float* __restrict__ part,
                                               const float* __restrict__ nll_class,
                                               const float* __restrict__ nll_edge,
                                               float* __restrict__ out,
                                               float inv_total) {
    float acc = 0.0f;
    for (int i = threadIdx.x; i < NPART; i += 256) acc += part[i];
    #pragma unroll
    for (int off = 32; off > 0; off >>= 1) acc += __shfl_down(acc, off, 64);
    __shared__ float s[4];
    int lane = threadIdx.x & 63;
    int w = threadIdx.x >> 6;
    if (lane == 0) s[w] = acc;
    __syncthreads();
    if (threadIdx.x == 0) {
        float mse = (s[0] + s[1] + s[2] + s[3]) * inv_total;
        float csum = 0.0f, esum = 0.0f;
        for (int b = 0; b < B; b++) { csum += nll_class[b]; esum += nll_edge[b]; }
        out[0] = mse + csum * (1.0f / B) + esum * (1.0f / B);
    }
}

extern "C" void kernel_launch(void* const* d_in, const int* in_sizes, int n_in,
                              void* d_out, int out_size, void* d_ws, size_t ws_size,
                              hipStream_t stream) {
    const float* pred_nodes = (const float*)d_in[0];
    const float* pred_edges = (const float*)d_in[1];
    const float* pred_dist  = (const float*)d_in[2];
    const float* ref_nodes  = (const float*)d_in[3];
    const float* ref_edges  = (const float*)d_in[4];
    const int*   ref_term   = (const int*)d_in[5];
    const float* ref_dist   = (const float*)d_in[6];

    float* out = (float*)d_out;   // [0] = loss, [1..64] = min_inds (as float)
    float* ws = (float*)d_ws;
    float* part = ws;             // NPART partials
    float* nllc = ws + NPART;     // B
    float* nlle = ws + NPART + B; // B

    int n_dist = in_sizes[2];     // 64*20*128*128 = 20971520
    int n4 = n_dist / 4;

    k_mse_partial<<<NPART, 256, 0, stream>>>(pred_dist, ref_dist, part, n4);
    k_batch<<<B, 64, 0, stream>>>(pred_nodes, pred_edges, ref_nodes, ref_edges,
                                  ref_term, out + 1, nllc, nlle);
    k_final<<<1, 256, 0, stream>>>(part, nllc, nlle, out, 1.0f / (float)n_dist);
}